// Round 1
// baseline (732.623 us; speedup 1.0000x reference)
//
#include <hip/hip_runtime.h>
#include <hip/hip_bf16.h>

#define N_NODES  100000
#define N_EDGES  1600000
#define N_GRAPHS 64
// IN_CH = HIDDEN = 128, OUT_CH = 2

// ---------------------------------------------------------------------------
// zero init: cnt[N_NODES] ints, pooled[64*128] floats, gcnt[64] floats
__global__ __launch_bounds__(256) void zero_kernel(int* __restrict__ cnt,
                                                   float* __restrict__ pooled,
                                                   float* __restrict__ gcnt) {
    int i = blockIdx.x * 256 + threadIdx.x;
    if (i < N_NODES) cnt[i] = 0;
    if (i < N_GRAPHS * 128) pooled[i] = 0.f;
    if (i < N_GRAPHS) gcnt[i] = 0.f;
}

// histogram of target nodes (in-degree, excluding self loop)
__global__ __launch_bounds__(256) void hist_kernel(const int* __restrict__ col,
                                                   int* __restrict__ cnt) {
    int i = blockIdx.x * 256 + threadIdx.x;
    if (i < N_EDGES) atomicAdd(&cnt[col[i]], 1);
}

// dinv[i] = rsqrt(in_deg + 1)   (self loop makes deg >= 1 always)
__global__ __launch_bounds__(256) void dinv_kernel(const int* __restrict__ cnt,
                                                   float* __restrict__ dinv) {
    int i = blockIdx.x * 256 + threadIdx.x;
    if (i < N_NODES) dinv[i] = rsqrtf((float)cnt[i] + 1.0f);
}

// scan stage 1: per-block (1024 elems) sums
__global__ __launch_bounds__(256) void scan1_kernel(const int* __restrict__ cnt,
                                                    int* __restrict__ bsum) {
    __shared__ int lds[256];
    int t = threadIdx.x;
    int base = blockIdx.x * 1024 + t * 4;
    int s = 0;
#pragma unroll
    for (int j = 0; j < 4; ++j) {
        int idx = base + j;
        if (idx < N_NODES) s += cnt[idx];
    }
    lds[t] = s;
    __syncthreads();
    for (int d = 128; d > 0; d >>= 1) {
        if (t < d) lds[t] += lds[t + d];
        __syncthreads();
    }
    if (t == 0) bsum[blockIdx.x] = lds[0];
}

// scan stage 2: serial exclusive scan of block sums (nb ~ 98, trivial)
__global__ void scan2_kernel(int* __restrict__ bsum, int nb) {
    if (threadIdx.x == 0 && blockIdx.x == 0) {
        int s = 0;
        for (int i = 0; i < nb; ++i) { int v = bsum[i]; bsum[i] = s; s += v; }
    }
}

// scan stage 3: full exclusive scan -> off[], cursor[] (copy of off)
__global__ __launch_bounds__(256) void scan3_kernel(const int* __restrict__ cnt,
                                                    const int* __restrict__ bsum,
                                                    int* __restrict__ off,
                                                    int* __restrict__ cur) {
    __shared__ int lds[256];
    int t = threadIdx.x;
    int base = blockIdx.x * 1024 + t * 4;
    int v[4];
    int ts = 0;
#pragma unroll
    for (int j = 0; j < 4; ++j) {
        int idx = base + j;
        v[j] = (idx < N_NODES) ? cnt[idx] : 0;
        ts += v[j];
    }
    lds[t] = ts;
    __syncthreads();
    for (int d = 1; d < 256; d <<= 1) {
        int x = (t >= d) ? lds[t - d] : 0;
        __syncthreads();
        lds[t] += x;
        __syncthreads();
    }
    int excl = lds[t] - ts + bsum[blockIdx.x];
#pragma unroll
    for (int j = 0; j < 4; ++j) {
        int idx = base + j;
        if (idx < N_NODES) { off[idx] = excl; cur[idx] = excl; }
        excl += v[j];
    }
    if (blockIdx.x == 0 && t == 0) off[N_NODES] = N_EDGES;
}

// counting-sort scatter: group source nodes by target
__global__ __launch_bounds__(256) void scatter_kernel(const int* __restrict__ row,
                                                      const int* __restrict__ col,
                                                      int* __restrict__ cur,
                                                      int* __restrict__ sortr) {
    int i = blockIdx.x * 256 + threadIdx.x;
    if (i < N_EDGES) {
        int c = col[i];
        int p = atomicAdd(&cur[c], 1);
        sortr[p] = row[i];
    }
}

// ---------------------------------------------------------------------------
// hs[n][:] = dinv[n] * (X[n][:] @ W)      (128x128 W staged in LDS)
// block = 256 threads, 64 nodes/block; thread computes 8 nodes x 4 channels
__global__ __launch_bounds__(256, 2) void gemm_premul_kernel(
    const float* __restrict__ X, const float* __restrict__ W,
    const float* __restrict__ dinv, float* __restrict__ out) {
    __shared__ float Ws[128 * 128];
    {
        const float4* src = (const float4*)W;
        float4* dst = (float4*)Ws;
        for (int i = threadIdx.x; i < 4096; i += 256) dst[i] = src[i];
    }
    __syncthreads();

    const int t = threadIdx.x;
    const int cg = (t & 31) * 4;   // channel group (4 channels)
    const int ng = t >> 5;         // node subgroup 0..7
    const long nbase = (long)blockIdx.x * 64 + (long)ng * 8;

    const float* xp[8];
#pragma unroll
    for (int i = 0; i < 8; ++i) {
        long n = nbase + i;
        if (n > N_NODES - 1) n = N_NODES - 1;   // clamp (tail block)
        xp[i] = X + n * 128;
    }

    float4 acc[8];
#pragma unroll
    for (int i = 0; i < 8; ++i) acc[i] = make_float4(0.f, 0.f, 0.f, 0.f);

    for (int k = 0; k < 128; k += 4) {
        float4 w0 = *(const float4*)&Ws[(k + 0) * 128 + cg];
        float4 w1 = *(const float4*)&Ws[(k + 1) * 128 + cg];
        float4 w2 = *(const float4*)&Ws[(k + 2) * 128 + cg];
        float4 w3 = *(const float4*)&Ws[(k + 3) * 128 + cg];
#pragma unroll
        for (int i = 0; i < 8; ++i) {
            float4 xv = *(const float4*)(xp[i] + k);
            acc[i].x = fmaf(xv.x, w0.x, acc[i].x);
            acc[i].y = fmaf(xv.x, w0.y, acc[i].y);
            acc[i].z = fmaf(xv.x, w0.z, acc[i].z);
            acc[i].w = fmaf(xv.x, w0.w, acc[i].w);
            acc[i].x = fmaf(xv.y, w1.x, acc[i].x);
            acc[i].y = fmaf(xv.y, w1.y, acc[i].y);
            acc[i].z = fmaf(xv.y, w1.z, acc[i].z);
            acc[i].w = fmaf(xv.y, w1.w, acc[i].w);
            acc[i].x = fmaf(xv.z, w2.x, acc[i].x);
            acc[i].y = fmaf(xv.z, w2.y, acc[i].y);
            acc[i].z = fmaf(xv.z, w2.z, acc[i].z);
            acc[i].w = fmaf(xv.z, w2.w, acc[i].w);
            acc[i].x = fmaf(xv.w, w3.x, acc[i].x);
            acc[i].y = fmaf(xv.w, w3.y, acc[i].y);
            acc[i].z = fmaf(xv.w, w3.z, acc[i].z);
            acc[i].w = fmaf(xv.w, w3.w, acc[i].w);
        }
    }

#pragma unroll
    for (int i = 0; i < 8; ++i) {
        long n = nbase + i;
        if (n < N_NODES) {
            float dv = dinv[n];
            float4 r = acc[i];
            r.x *= dv; r.y *= dv; r.z *= dv; r.w *= dv;
            *(float4*)&out[n * 128 + cg] = r;
        }
    }
}

// ---------------------------------------------------------------------------
// out[c][:] = relu(dinv[c] * (sum_{r in N(c)} hs[r][:] + hs[c][:]) + bias)
// one wave per node; lane owns 2 channels (float2, 512B coalesced per row)
__global__ __launch_bounds__(256) void agg_kernel(const float* __restrict__ hs,
                                                  const int* __restrict__ sortr,
                                                  const int* __restrict__ off,
                                                  const float* __restrict__ dinv,
                                                  const float* __restrict__ bias,
                                                  float* __restrict__ out) {
    int wid = (blockIdx.x * 256 + threadIdx.x) >> 6;
    int lane = threadIdx.x & 63;
    if (wid >= N_NODES) return;
    const int c = wid;
    const int e0 = off[c], e1 = off[c + 1];
    const long chb = 2 * lane;

    // self-loop term
    float2 s = *(const float2*)&hs[(long)c * 128 + chb];
    float a0x = s.x, a0y = s.y;
    float a1x = 0.f, a1y = 0.f, a2x = 0.f, a2y = 0.f, a3x = 0.f, a3y = 0.f;

    int e = e0;
    for (; e + 4 <= e1; e += 4) {
        int r0 = sortr[e + 0], r1 = sortr[e + 1];
        int r2 = sortr[e + 2], r3 = sortr[e + 3];
        float2 v0 = *(const float2*)&hs[(long)r0 * 128 + chb];
        float2 v1 = *(const float2*)&hs[(long)r1 * 128 + chb];
        float2 v2 = *(const float2*)&hs[(long)r2 * 128 + chb];
        float2 v3 = *(const float2*)&hs[(long)r3 * 128 + chb];
        a0x += v0.x; a0y += v0.y;
        a1x += v1.x; a1y += v1.y;
        a2x += v2.x; a2y += v2.y;
        a3x += v3.x; a3y += v3.y;
    }
    for (; e < e1; ++e) {
        int r0 = sortr[e];
        float2 v0 = *(const float2*)&hs[(long)r0 * 128 + chb];
        a0x += v0.x; a0y += v0.y;
    }
    float ax = (a0x + a1x) + (a2x + a3x);
    float ay = (a0y + a1y) + (a2y + a3y);

    float dv = dinv[c];
    float2 b = *(const float2*)&bias[chb];
    float2 r;
    r.x = fmaxf(fmaf(ax, dv, b.x), 0.f);
    r.y = fmaxf(fmaf(ay, dv, b.y), 0.f);
    *(float2*)&out[(long)c * 128 + chb] = r;
}

// ---------------------------------------------------------------------------
// mean-pool stage 1: per-wave chunk of 32 sorted nodes, flush on graph change
__global__ __launch_bounds__(256) void pool_kernel(const float* __restrict__ h,
                                                   const int* __restrict__ batch,
                                                   float* __restrict__ pooled,
                                                   float* __restrict__ gcnt) {
    int wid = (blockIdx.x * 256 + threadIdx.x) >> 6;
    int lane = threadIdx.x & 63;
    long n0 = (long)wid * 32;
    if (n0 >= N_NODES) return;
    long n1 = n0 + 32;
    if (n1 > N_NODES) n1 = N_NODES;
    const long chb = 2 * lane;

    int g = batch[n0];
    float ax = 0.f, ay = 0.f;
    int run = 0;
    for (long n = n0; n < n1; ++n) {
        int gn = batch[n];
        if (gn != g) {   // wave-uniform branch (batch is sorted)
            atomicAdd(&pooled[g * 128 + chb], ax);
            atomicAdd(&pooled[g * 128 + chb + 1], ay);
            if (lane == 0) atomicAdd(&gcnt[g], (float)run);
            g = gn; ax = 0.f; ay = 0.f; run = 0;
        }
        float2 v = *(const float2*)&h[n * 128 + chb];
        ax += v.x; ay += v.y; run++;
    }
    atomicAdd(&pooled[g * 128 + chb], ax);
    atomicAdd(&pooled[g * 128 + chb + 1], ay);
    if (lane == 0) atomicAdd(&gcnt[g], (float)run);
}

// final: out[g][o] = (pooled[g][:]/cnt) @ Wlin[:,o] + blin[o]    (64x2)
__global__ void final_kernel(const float* __restrict__ pooled,
                             const float* __restrict__ gcnt,
                             const float* __restrict__ Wlin,
                             const float* __restrict__ blin,
                             float* __restrict__ out) {
    int t = threadIdx.x;
    if (t >= N_GRAPHS * 2) return;
    int g = t >> 1, o = t & 1;
    float c = gcnt[g];
    if (c < 1.f) c = 1.f;
    float s = 0.f;
    for (int k = 0; k < 128; ++k)
        s += (pooled[g * 128 + k] / c) * Wlin[k * 2 + o];
    out[g * 2 + o] = s + blin[o];
}

// ---------------------------------------------------------------------------
extern "C" void kernel_launch(void* const* d_in, const int* in_sizes, int n_in,
                              void* d_out, int out_size, void* d_ws, size_t ws_size,
                              hipStream_t stream) {
    const float* x     = (const float*)d_in[0];
    const int*   row   = (const int*)d_in[1];
    const int*   col   = row + N_EDGES;
    const int*   batch = (const int*)d_in[2];
    const float* W1    = (const float*)d_in[3];
    const float* b1    = (const float*)d_in[4];
    const float* W2    = (const float*)d_in[5];
    const float* b2    = (const float*)d_in[6];
    const float* Wlin  = (const float*)d_in[7];
    const float* blin  = (const float*)d_in[8];
    float* out = (float*)d_out;

    char* w = (char*)d_ws;
    size_t p = 0;
    auto alloc = [&](size_t bytes) -> void* {
        void* r = w + p;
        p += (bytes + 511) & ~(size_t)511;
        return r;
    };
    int*   cnt    = (int*)alloc((size_t)N_NODES * 4);
    int*   off    = (int*)alloc((size_t)(N_NODES + 1) * 4);
    int*   cur    = (int*)alloc((size_t)N_NODES * 4);
    int*   bsum   = (int*)alloc(128 * 4);
    float* dinv   = (float*)alloc((size_t)N_NODES * 4);
    int*   sortr  = (int*)alloc((size_t)N_EDGES * 4);
    float* hs     = (float*)alloc((size_t)N_NODES * 128 * 4);
    float* hbuf   = (float*)alloc((size_t)N_NODES * 128 * 4);
    float* pooled = (float*)alloc((size_t)N_GRAPHS * 128 * 4);
    float* gcnt   = (float*)alloc((size_t)N_GRAPHS * 4);
    (void)ws_size; (void)in_sizes; (void)n_in; (void)out_size;

    const int nb_scan = (N_NODES + 1023) / 1024;       // 98
    const int nb_edge = (N_EDGES + 255) / 256;         // 6250
    const int nb_node = (N_NODES + 255) / 256;         // 391

    zero_kernel<<<nb_node, 256, 0, stream>>>(cnt, pooled, gcnt);
    hist_kernel<<<nb_edge, 256, 0, stream>>>(col, cnt);
    dinv_kernel<<<nb_node, 256, 0, stream>>>(cnt, dinv);
    scan1_kernel<<<nb_scan, 256, 0, stream>>>(cnt, bsum);
    scan2_kernel<<<1, 64, 0, stream>>>(bsum, nb_scan);
    scan3_kernel<<<nb_scan, 256, 0, stream>>>(cnt, bsum, off, cur);
    scatter_kernel<<<nb_edge, 256, 0, stream>>>(row, col, cur, sortr);

    // layer 1
    gemm_premul_kernel<<<(N_NODES + 63) / 64, 256, 0, stream>>>(x, W1, dinv, hs);
    agg_kernel<<<(N_NODES * 64 + 255) / 256, 256, 0, stream>>>(hs, sortr, off, dinv, b1, hbuf);
    // layer 2
    gemm_premul_kernel<<<(N_NODES + 63) / 64, 256, 0, stream>>>(hbuf, W2, dinv, hs);
    agg_kernel<<<(N_NODES * 64 + 255) / 256, 256, 0, stream>>>(hs, sortr, off, dinv, b2, hbuf);

    // pool + classifier
    pool_kernel<<<(((N_NODES + 31) / 32) * 64 + 255) / 256, 256, 0, stream>>>(hbuf, batch, pooled, gcnt);
    final_kernel<<<1, 128, 0, stream>>>(pooled, gcnt, Wlin, blin, out);
}

// Round 3
// 647.760 us; speedup vs baseline: 1.1310x; 1.1310x over previous
//
#include <hip/hip_runtime.h>
#include <hip/hip_bf16.h>
#include <hip/hip_fp16.h>

#define N_NODES  100000
#define N_EDGES  1600000
#define N_GRAPHS 64
// IN_CH = HIDDEN = 128, OUT_CH = 2

// ---------------------------------------------------------------------------
// zero init: cnt[N_NODES] ints, pooled[64*128] floats, gcnt[64] floats
__global__ __launch_bounds__(256) void zero_kernel(int* __restrict__ cnt,
                                                   float* __restrict__ pooled,
                                                   float* __restrict__ gcnt) {
    int i = blockIdx.x * 256 + threadIdx.x;
    if (i < N_NODES) cnt[i] = 0;
    if (i < N_GRAPHS * 128) pooled[i] = 0.f;
    if (i < N_GRAPHS) gcnt[i] = 0.f;
}

// histogram of target nodes (in-degree, excluding self loop), 4 edges/thread
__global__ __launch_bounds__(256) void hist_kernel(const int4* __restrict__ col4,
                                                   int* __restrict__ cnt) {
    int i = blockIdx.x * 256 + threadIdx.x;
    if (i < N_EDGES / 4) {
        int4 c = col4[i];
        atomicAdd(&cnt[c.x], 1);
        atomicAdd(&cnt[c.y], 1);
        atomicAdd(&cnt[c.z], 1);
        atomicAdd(&cnt[c.w], 1);
    }
}

// scan stage 1: per-block (1024 elems) sums
__global__ __launch_bounds__(256) void scan1_kernel(const int* __restrict__ cnt,
                                                    int* __restrict__ bsum) {
    __shared__ int lds[256];
    int t = threadIdx.x;
    int base = blockIdx.x * 1024 + t * 4;
    int s = 0;
#pragma unroll
    for (int j = 0; j < 4; ++j) {
        int idx = base + j;
        if (idx < N_NODES) s += cnt[idx];
    }
    lds[t] = s;
    __syncthreads();
    for (int d = 128; d > 0; d >>= 1) {
        if (t < d) lds[t] += lds[t + d];
        __syncthreads();
    }
    if (t == 0) bsum[blockIdx.x] = lds[0];
}

// scan stage 2: serial exclusive scan of block sums (nb ~ 98, trivial)
__global__ void scan2_kernel(int* __restrict__ bsum, int nb) {
    if (threadIdx.x == 0 && blockIdx.x == 0) {
        int s = 0;
        for (int i = 0; i < nb; ++i) { int v = bsum[i]; bsum[i] = s; s += v; }
    }
}

// scan stage 3: full exclusive scan -> off[], cursor[], and dinv[] (fused)
__global__ __launch_bounds__(256) void scan3_kernel(const int* __restrict__ cnt,
                                                    const int* __restrict__ bsum,
                                                    int* __restrict__ off,
                                                    int* __restrict__ cur,
                                                    float* __restrict__ dinv) {
    __shared__ int lds[256];
    int t = threadIdx.x;
    int base = blockIdx.x * 1024 + t * 4;
    int v[4];
    int ts = 0;
#pragma unroll
    for (int j = 0; j < 4; ++j) {
        int idx = base + j;
        v[j] = (idx < N_NODES) ? cnt[idx] : 0;
        ts += v[j];
    }
    lds[t] = ts;
    __syncthreads();
    for (int d = 1; d < 256; d <<= 1) {
        int x = (t >= d) ? lds[t - d] : 0;
        __syncthreads();
        lds[t] += x;
        __syncthreads();
    }
    int excl = lds[t] - ts + bsum[blockIdx.x];
#pragma unroll
    for (int j = 0; j < 4; ++j) {
        int idx = base + j;
        if (idx < N_NODES) {
            off[idx] = excl;
            cur[idx] = excl;
            dinv[idx] = rsqrtf((float)v[j] + 1.0f);
        }
        excl += v[j];
    }
    if (blockIdx.x == 0 && t == 0) off[N_NODES] = N_EDGES;
}

// counting-sort scatter: group source nodes by target, 4 edges/thread
__global__ __launch_bounds__(256) void scatter_kernel(const int4* __restrict__ row4,
                                                      const int4* __restrict__ col4,
                                                      int* __restrict__ cur,
                                                      int* __restrict__ sortr) {
    int i = blockIdx.x * 256 + threadIdx.x;
    if (i < N_EDGES / 4) {
        int4 r = row4[i];
        int4 c = col4[i];
        int p0 = atomicAdd(&cur[c.x], 1); sortr[p0] = r.x;
        int p1 = atomicAdd(&cur[c.y], 1); sortr[p1] = r.y;
        int p2 = atomicAdd(&cur[c.z], 1); sortr[p2] = r.z;
        int p3 = atomicAdd(&cur[c.w], 1); sortr[p3] = r.w;
    }
}

// ---------------------------------------------------------------------------
// hs[n][:] = fp16( dinv[n] * (X[n][:] @ W) )    (128x128 W staged in LDS)
// block = 256 threads, 64 nodes/block; thread computes 8 nodes x 4 channels
struct h4pack { __half2 a, b; };

__global__ __launch_bounds__(256, 2) void gemm_premul_kernel(
    const float* __restrict__ X, const float* __restrict__ W,
    const float* __restrict__ dinv, __half* __restrict__ out) {
    __shared__ float Ws[128 * 128];
    {
        const float4* src = (const float4*)W;
        float4* dst = (float4*)Ws;
        for (int i = threadIdx.x; i < 4096; i += 256) dst[i] = src[i];
    }
    __syncthreads();

    const int t = threadIdx.x;
    const int cg = (t & 31) * 4;   // channel group (4 channels)
    const int ng = t >> 5;         // node subgroup 0..7
    const long nbase = (long)blockIdx.x * 64 + (long)ng * 8;

    const float* xp[8];
#pragma unroll
    for (int i = 0; i < 8; ++i) {
        long n = nbase + i;
        if (n > N_NODES - 1) n = N_NODES - 1;   // clamp (tail block)
        xp[i] = X + n * 128;
    }

    float4 acc[8];
#pragma unroll
    for (int i = 0; i < 8; ++i) acc[i] = make_float4(0.f, 0.f, 0.f, 0.f);

    for (int k = 0; k < 128; k += 4) {
        float4 w0 = *(const float4*)&Ws[(k + 0) * 128 + cg];
        float4 w1 = *(const float4*)&Ws[(k + 1) * 128 + cg];
        float4 w2 = *(const float4*)&Ws[(k + 2) * 128 + cg];
        float4 w3 = *(const float4*)&Ws[(k + 3) * 128 + cg];
#pragma unroll
        for (int i = 0; i < 8; ++i) {
            float4 xv = *(const float4*)(xp[i] + k);
            acc[i].x = fmaf(xv.x, w0.x, acc[i].x);
            acc[i].y = fmaf(xv.x, w0.y, acc[i].y);
            acc[i].z = fmaf(xv.x, w0.z, acc[i].z);
            acc[i].w = fmaf(xv.x, w0.w, acc[i].w);
            acc[i].x = fmaf(xv.y, w1.x, acc[i].x);
            acc[i].y = fmaf(xv.y, w1.y, acc[i].y);
            acc[i].z = fmaf(xv.y, w1.z, acc[i].z);
            acc[i].w = fmaf(xv.y, w1.w, acc[i].w);
            acc[i].x = fmaf(xv.z, w2.x, acc[i].x);
            acc[i].y = fmaf(xv.z, w2.y, acc[i].y);
            acc[i].z = fmaf(xv.z, w2.z, acc[i].z);
            acc[i].w = fmaf(xv.z, w2.w, acc[i].w);
            acc[i].x = fmaf(xv.w, w3.x, acc[i].x);
            acc[i].y = fmaf(xv.w, w3.y, acc[i].y);
            acc[i].z = fmaf(xv.w, w3.z, acc[i].z);
            acc[i].w = fmaf(xv.w, w3.w, acc[i].w);
        }
    }

#pragma unroll
    for (int i = 0; i < 8; ++i) {
        long n = nbase + i;
        if (n < N_NODES) {
            float dv = dinv[n];
            float4 r = acc[i];
            h4pack p;
            p.a = __floats2half2_rn(r.x * dv, r.y * dv);
            p.b = __floats2half2_rn(r.z * dv, r.w * dv);
            *(h4pack*)&out[n * 128 + cg] = p;
        }
    }
}

// ---------------------------------------------------------------------------
// out[c][:] = relu(dinv[c] * (sum_{r in N(c)} hs[r][:] + hs[c][:]) + bias)
// one wave per node; lane owns 2 channels (half2 gather = 256B/row coalesced)
__global__ __launch_bounds__(256) void agg_kernel(const __half* __restrict__ hs,
                                                  const int* __restrict__ sortr,
                                                  const int* __restrict__ off,
                                                  const float* __restrict__ dinv,
                                                  const float* __restrict__ bias,
                                                  float* __restrict__ out) {
    int wid = (blockIdx.x * 256 + threadIdx.x) >> 6;
    int lane = threadIdx.x & 63;
    if (wid >= N_NODES) return;
    const int c = wid;
    const int e0 = off[c], e1 = off[c + 1];
    const long chb = 2 * lane;

    // self-loop term
    float2 s = __half22float2(*(const __half2*)&hs[(long)c * 128 + chb]);
    float a0x = s.x, a0y = s.y;
    float a1x = 0.f, a1y = 0.f, a2x = 0.f, a2y = 0.f, a3x = 0.f, a3y = 0.f;

    int e = e0;
    for (; e + 4 <= e1; e += 4) {
        int r0 = sortr[e + 0], r1 = sortr[e + 1];
        int r2 = sortr[e + 2], r3 = sortr[e + 3];
        float2 v0 = __half22float2(*(const __half2*)&hs[(long)r0 * 128 + chb]);
        float2 v1 = __half22float2(*(const __half2*)&hs[(long)r1 * 128 + chb]);
        float2 v2 = __half22float2(*(const __half2*)&hs[(long)r2 * 128 + chb]);
        float2 v3 = __half22float2(*(const __half2*)&hs[(long)r3 * 128 + chb]);
        a0x += v0.x; a0y += v0.y;
        a1x += v1.x; a1y += v1.y;
        a2x += v2.x; a2y += v2.y;
        a3x += v3.x; a3y += v3.y;
    }
    for (; e < e1; ++e) {
        int r0 = sortr[e];
        float2 v0 = __half22float2(*(const __half2*)&hs[(long)r0 * 128 + chb]);
        a0x += v0.x; a0y += v0.y;
    }
    float ax = (a0x + a1x) + (a2x + a3x);
    float ay = (a0y + a1y) + (a2y + a3y);

    float dv = dinv[c];
    float2 b = *(const float2*)&bias[chb];
    float2 r;
    r.x = fmaxf(fmaf(ax, dv, b.x), 0.f);
    r.y = fmaxf(fmaf(ay, dv, b.y), 0.f);
    *(float2*)&out[(long)c * 128 + chb] = r;
}

// ---------------------------------------------------------------------------
// mean-pool stage 1: per-wave chunk of 32 sorted nodes, flush on graph change
__global__ __launch_bounds__(256) void pool_kernel(const float* __restrict__ h,
                                                   const int* __restrict__ batch,
                                                   float* __restrict__ pooled,
                                                   float* __restrict__ gcnt) {
    int wid = (blockIdx.x * 256 + threadIdx.x) >> 6;
    int lane = threadIdx.x & 63;
    long n0 = (long)wid * 32;
    if (n0 >= N_NODES) return;
    long n1 = n0 + 32;
    if (n1 > N_NODES) n1 = N_NODES;
    const long chb = 2 * lane;

    int g = batch[n0];
    float ax = 0.f, ay = 0.f;
    int run = 0;
    for (long n = n0; n < n1; ++n) {
        int gn = batch[n];
        if (gn != g) {   // wave-uniform branch (batch is sorted)
            atomicAdd(&pooled[g * 128 + chb], ax);
            atomicAdd(&pooled[g * 128 + chb + 1], ay);
            if (lane == 0) atomicAdd(&gcnt[g], (float)run);
            g = gn; ax = 0.f; ay = 0.f; run = 0;
        }
        float2 v = *(const float2*)&h[n * 128 + chb];
        ax += v.x; ay += v.y; run++;
    }
    atomicAdd(&pooled[g * 128 + chb], ax);
    atomicAdd(&pooled[g * 128 + chb + 1], ay);
    if (lane == 0) atomicAdd(&gcnt[g], (float)run);
}

// final: out[g][o] = (pooled[g][:]/cnt) @ Wlin[:,o] + blin[o]    (64x2)
__global__ void final_kernel(const float* __restrict__ pooled,
                             const float* __restrict__ gcnt,
                             const float* __restrict__ Wlin,
                             const float* __restrict__ blin,
                             float* __restrict__ out) {
    int t = threadIdx.x;
    if (t >= N_GRAPHS * 2) return;
    int g = t >> 1, o = t & 1;
    float c = gcnt[g];
    if (c < 1.f) c = 1.f;
    float s = 0.f;
    for (int k = 0; k < 128; ++k)
        s += (pooled[g * 128 + k] / c) * Wlin[k * 2 + o];
    out[g * 2 + o] = s + blin[o];
}

// ---------------------------------------------------------------------------
extern "C" void kernel_launch(void* const* d_in, const int* in_sizes, int n_in,
                              void* d_out, int out_size, void* d_ws, size_t ws_size,
                              hipStream_t stream) {
    const float* x     = (const float*)d_in[0];
    const int*   row   = (const int*)d_in[1];
    const int*   col   = row + N_EDGES;
    const int*   batch = (const int*)d_in[2];
    const float* W1    = (const float*)d_in[3];
    const float* b1    = (const float*)d_in[4];
    const float* W2    = (const float*)d_in[5];
    const float* b2    = (const float*)d_in[6];
    const float* Wlin  = (const float*)d_in[7];
    const float* blin  = (const float*)d_in[8];
    float* out = (float*)d_out;

    char* w = (char*)d_ws;
    size_t p = 0;
    auto alloc = [&](size_t bytes) -> void* {
        void* r = w + p;
        p += (bytes + 511) & ~(size_t)511;
        return r;
    };
    int*    cnt    = (int*)alloc((size_t)N_NODES * 4);
    int*    off    = (int*)alloc((size_t)(N_NODES + 1) * 4);
    int*    cur    = (int*)alloc((size_t)N_NODES * 4);
    int*    bsum   = (int*)alloc(128 * 4);
    float*  dinv   = (float*)alloc((size_t)N_NODES * 4);
    int*    sortr  = (int*)alloc((size_t)N_EDGES * 4);
    __half* hs     = (__half*)alloc((size_t)N_NODES * 128 * 2);
    float*  hbuf   = (float*)alloc((size_t)N_NODES * 128 * 4);
    float*  pooled = (float*)alloc((size_t)N_GRAPHS * 128 * 4);
    float*  gcnt   = (float*)alloc((size_t)N_GRAPHS * 4);
    (void)ws_size; (void)in_sizes; (void)n_in; (void)out_size;

    const int nb_scan  = (N_NODES + 1023) / 1024;       // 98
    const int nb_edge4 = (N_EDGES / 4 + 255) / 256;     // 1563
    const int nb_node  = (N_NODES + 255) / 256;         // 391

    zero_kernel<<<nb_node, 256, 0, stream>>>(cnt, pooled, gcnt);
    hist_kernel<<<nb_edge4, 256, 0, stream>>>((const int4*)col, cnt);
    scan1_kernel<<<nb_scan, 256, 0, stream>>>(cnt, bsum);
    scan2_kernel<<<1, 64, 0, stream>>>(bsum, nb_scan);
    scan3_kernel<<<nb_scan, 256, 0, stream>>>(cnt, bsum, off, cur, dinv);
    scatter_kernel<<<nb_edge4, 256, 0, stream>>>((const int4*)row, (const int4*)col, cur, sortr);

    // layer 1
    gemm_premul_kernel<<<(N_NODES + 63) / 64, 256, 0, stream>>>(x, W1, dinv, hs);
    agg_kernel<<<(N_NODES * 64 + 255) / 256, 256, 0, stream>>>(hs, sortr, off, dinv, b1, hbuf);
    // layer 2
    gemm_premul_kernel<<<(N_NODES + 63) / 64, 256, 0, stream>>>(hbuf, W2, dinv, hs);
    agg_kernel<<<(N_NODES * 64 + 255) / 256, 256, 0, stream>>>(hs, sortr, off, dinv, b2, hbuf);

    // pool + classifier
    pool_kernel<<<(((N_NODES + 31) / 32) * 64 + 255) / 256, 256, 0, stream>>>(hbuf, batch, pooled, gcnt);
    final_kernel<<<1, 128, 0, stream>>>(pooled, gcnt, Wlin, blin, out);
}

// Round 4
// 476.319 us; speedup vs baseline: 1.5381x; 1.3599x over previous
//
#include <hip/hip_runtime.h>
#include <hip/hip_bf16.h>
#include <hip/hip_fp16.h>

#define N_NODES  100000
#define N_EDGES  1600000
#define N_GRAPHS 64
// IN_CH = HIDDEN = 128, OUT_CH = 2

// Sort geometry: 256 buckets x 391 cols, 391 blocks x 4096 edges
#define NB       256          // buckets
#define BSZ      391          // cols per bucket (256*391 = 100096 >= 100000)
#define NE4      (N_EDGES/4)  // 400000 int4 elements
#define NBLK     391          // ceil(400000/1024) edge blocks (4096 edges each)

// ---------------------------------------------------------------------------
// zero init: pooled[64*128] floats, gcnt[64] floats
__global__ __launch_bounds__(256) void zero_kernel(float* __restrict__ pooled,
                                                   float* __restrict__ gcnt) {
    int i = blockIdx.x * 256 + threadIdx.x;
    if (i < N_GRAPHS * 128) pooled[i] = 0.f;
    if (i < N_GRAPHS) gcnt[i] = 0.f;
}

// ---------------------------------------------------------------------------
// Pass A1: per-block 256-bucket histogram of col -> blockcnt[blk][bucket]
__global__ __launch_bounds__(256) void sortcount_kernel(const int4* __restrict__ col4,
                                                        int* __restrict__ blockcnt) {
    __shared__ int hist[NB];
    int t = threadIdx.x, blk = blockIdx.x;
    hist[t] = 0;
    __syncthreads();
#pragma unroll
    for (int j = 0; j < 4; ++j) {
        int i = blk * 1024 + j * 256 + t;
        if (i < NE4) {
            int4 c = col4[i];
            atomicAdd(&hist[c.x / BSZ], 1);
            atomicAdd(&hist[c.y / BSZ], 1);
            atomicAdd(&hist[c.z / BSZ], 1);
            atomicAdd(&hist[c.w / BSZ], 1);
        }
    }
    __syncthreads();
    blockcnt[blk * NB + t] = hist[t];
}

// Pass A2a: per-bucket exclusive scan across the 391 blocks (in place),
// one workgroup per bucket; emits bucket totals.
__global__ __launch_bounds__(256) void sortscan_kernel(int* __restrict__ blockcnt,
                                                       int* __restrict__ buckettotal) {
    int b = blockIdx.x, t = threadIdx.x;
    __shared__ int sc[256];
    int e0 = 2 * t, e1 = 2 * t + 1;
    int v0 = (e0 < NBLK) ? blockcnt[e0 * NB + b] : 0;
    int v1 = (e1 < NBLK) ? blockcnt[e1 * NB + b] : 0;
    int ps = v0 + v1;
    sc[t] = ps;
    __syncthreads();
    for (int d = 1; d < 256; d <<= 1) {
        int x = (t >= d) ? sc[t - d] : 0;
        __syncthreads();
        sc[t] += x;
        __syncthreads();
    }
    int ex = sc[t] - ps;   // exclusive prefix of this thread's pair
    if (e0 < NBLK) blockcnt[e0 * NB + b] = ex;
    if (e1 < NBLK) blockcnt[e1 * NB + b] = ex + v0;
    if (t == 255) buckettotal[b] = sc[255];
}

// Pass A2b: exclusive scan of 256 bucket totals -> bucket_base; off[N]=E
__global__ __launch_bounds__(256) void sortbase_kernel(const int* __restrict__ buckettotal,
                                                       int* __restrict__ bucket_base,
                                                       int* __restrict__ off) {
    __shared__ int sc[256];
    int t = threadIdx.x;
    int v = buckettotal[t];
    sc[t] = v;
    __syncthreads();
    for (int d = 1; d < 256; d <<= 1) {
        int x = (t >= d) ? sc[t - d] : 0;
        __syncthreads();
        sc[t] += x;
        __syncthreads();
    }
    bucket_base[t] = sc[t] - v;
    if (t == 255) {
        bucket_base[256] = sc[255];
        off[N_NODES] = N_EDGES;
    }
}

// Pass A3: scatter (row,col) pairs into bucket-grouped pairbuf using
// LDS absolute cursors (bucket_base + per-block prefix). No global atomics.
__global__ __launch_bounds__(256) void sortscatter_kernel(const int4* __restrict__ row4,
                                                          const int4* __restrict__ col4,
                                                          const int* __restrict__ blockpre,
                                                          const int* __restrict__ bucket_base,
                                                          int2* __restrict__ pairs) {
    __shared__ int cur[NB];
    int t = threadIdx.x, blk = blockIdx.x;
    cur[t] = bucket_base[t] + blockpre[blk * NB + t];
    __syncthreads();
#pragma unroll
    for (int j = 0; j < 4; ++j) {
        int i = blk * 1024 + j * 256 + t;
        if (i < NE4) {
            int4 r = row4[i];
            int4 c = col4[i];
            int p0 = atomicAdd(&cur[c.x / BSZ], 1); pairs[p0] = make_int2(r.x, c.x);
            int p1 = atomicAdd(&cur[c.y / BSZ], 1); pairs[p1] = make_int2(r.y, c.y);
            int p2 = atomicAdd(&cur[c.z / BSZ], 1); pairs[p2] = make_int2(r.z, c.z);
            int p3 = atomicAdd(&cur[c.w / BSZ], 1); pairs[p3] = make_int2(r.w, c.w);
        }
    }
}

// Pass B: one workgroup per bucket. LDS histogram over <=391 local cols,
// LDS scan -> off/dinv written directly; local counting-sort into sortr
// (destination region is contiguous & L2-resident, ~50KB).
__global__ __launch_bounds__(256) void sortlocal_kernel(const int2* __restrict__ pairs,
                                                        const int* __restrict__ bucket_base,
                                                        const int* __restrict__ buckettotal,
                                                        int* __restrict__ sortr,
                                                        int* __restrict__ off,
                                                        float* __restrict__ dinv) {
    int b = blockIdx.x, t = threadIdx.x;
    int base = bucket_base[b];
    int cnt  = buckettotal[b];
    int c0   = b * BSZ;
    int nc   = N_NODES - c0; if (nc > BSZ) nc = BSZ;

    __shared__ int hist[BSZ];
    __shared__ int sc[256];
    for (int i = t; i < nc; i += 256) hist[i] = 0;
    __syncthreads();
    for (int i = t; i < cnt; i += 256) {
        int2 pc = pairs[base + i];
        atomicAdd(&hist[pc.y - c0], 1);
    }
    __syncthreads();
    // exclusive scan over nc (<=391) entries, 2 per thread
    int e0 = 2 * t, e1 = 2 * t + 1;
    int h0 = (e0 < nc) ? hist[e0] : 0;
    int h1 = (e1 < nc) ? hist[e1] : 0;
    int ps = h0 + h1;
    sc[t] = ps;
    __syncthreads();
    for (int d = 1; d < 256; d <<= 1) {
        int x = (t >= d) ? sc[t - d] : 0;
        __syncthreads();
        sc[t] += x;
        __syncthreads();
    }
    int ex = sc[t] - ps;
    if (e0 < nc) { off[c0 + e0] = base + ex;      dinv[c0 + e0] = rsqrtf((float)h0 + 1.f); }
    if (e1 < nc) { off[c0 + e1] = base + ex + h0; dinv[c0 + e1] = rsqrtf((float)h1 + 1.f); }
    __syncthreads();   // all reads of hist done before overwrite
    if (e0 < nc) hist[e0] = base + ex;
    if (e1 < nc) hist[e1] = base + ex + h0;
    __syncthreads();
    for (int i = t; i < cnt; i += 256) {
        int2 pc = pairs[base + i];      // L2-hit (read above)
        int pos = atomicAdd(&hist[pc.y - c0], 1);
        sortr[pos] = pc.x;
    }
}

// ---------------------------------------------------------------------------
// hs[n][:] = fp16( dinv[n] * (X[n][:] @ W) )    (128x128 W staged in LDS)
struct h4pack { __half2 a, b; };

__global__ __launch_bounds__(256, 2) void gemm_premul_kernel(
    const float* __restrict__ X, const float* __restrict__ W,
    const float* __restrict__ dinv, __half* __restrict__ out) {
    __shared__ float Ws[128 * 128];
    {
        const float4* src = (const float4*)W;
        float4* dst = (float4*)Ws;
        for (int i = threadIdx.x; i < 4096; i += 256) dst[i] = src[i];
    }
    __syncthreads();

    const int t = threadIdx.x;
    const int cg = (t & 31) * 4;
    const int ng = t >> 5;
    const long nbase = (long)blockIdx.x * 64 + (long)ng * 8;

    const float* xp[8];
#pragma unroll
    for (int i = 0; i < 8; ++i) {
        long n = nbase + i;
        if (n > N_NODES - 1) n = N_NODES - 1;
        xp[i] = X + n * 128;
    }

    float4 acc[8];
#pragma unroll
    for (int i = 0; i < 8; ++i) acc[i] = make_float4(0.f, 0.f, 0.f, 0.f);

    for (int k = 0; k < 128; k += 4) {
        float4 w0 = *(const float4*)&Ws[(k + 0) * 128 + cg];
        float4 w1 = *(const float4*)&Ws[(k + 1) * 128 + cg];
        float4 w2 = *(const float4*)&Ws[(k + 2) * 128 + cg];
        float4 w3 = *(const float4*)&Ws[(k + 3) * 128 + cg];
#pragma unroll
        for (int i = 0; i < 8; ++i) {
            float4 xv = *(const float4*)(xp[i] + k);
            acc[i].x = fmaf(xv.x, w0.x, acc[i].x);
            acc[i].y = fmaf(xv.x, w0.y, acc[i].y);
            acc[i].z = fmaf(xv.x, w0.z, acc[i].z);
            acc[i].w = fmaf(xv.x, w0.w, acc[i].w);
            acc[i].x = fmaf(xv.y, w1.x, acc[i].x);
            acc[i].y = fmaf(xv.y, w1.y, acc[i].y);
            acc[i].z = fmaf(xv.y, w1.z, acc[i].z);
            acc[i].w = fmaf(xv.y, w1.w, acc[i].w);
            acc[i].x = fmaf(xv.z, w2.x, acc[i].x);
            acc[i].y = fmaf(xv.z, w2.y, acc[i].y);
            acc[i].z = fmaf(xv.z, w2.z, acc[i].z);
            acc[i].w = fmaf(xv.z, w2.w, acc[i].w);
            acc[i].x = fmaf(xv.w, w3.x, acc[i].x);
            acc[i].y = fmaf(xv.w, w3.y, acc[i].y);
            acc[i].z = fmaf(xv.w, w3.z, acc[i].z);
            acc[i].w = fmaf(xv.w, w3.w, acc[i].w);
        }
    }

#pragma unroll
    for (int i = 0; i < 8; ++i) {
        long n = nbase + i;
        if (n < N_NODES) {
            float dv = dinv[n];
            float4 r = acc[i];
            h4pack p;
            p.a = __floats2half2_rn(r.x * dv, r.y * dv);
            p.b = __floats2half2_rn(r.z * dv, r.w * dv);
            *(h4pack*)&out[n * 128 + cg] = p;
        }
    }
}

// ---------------------------------------------------------------------------
// out[c][:] = relu(dinv[c] * (sum_{r in N(c)} hs[r][:] + hs[c][:]) + bias)
__global__ __launch_bounds__(256) void agg_kernel(const __half* __restrict__ hs,
                                                  const int* __restrict__ sortr,
                                                  const int* __restrict__ off,
                                                  const float* __restrict__ dinv,
                                                  const float* __restrict__ bias,
                                                  float* __restrict__ out) {
    int wid = (blockIdx.x * 256 + threadIdx.x) >> 6;
    int lane = threadIdx.x & 63;
    if (wid >= N_NODES) return;
    const int c = wid;
    const int e0 = off[c], e1 = off[c + 1];
    const long chb = 2 * lane;

    float2 s = __half22float2(*(const __half2*)&hs[(long)c * 128 + chb]);
    float a0x = s.x, a0y = s.y;
    float a1x = 0.f, a1y = 0.f, a2x = 0.f, a2y = 0.f, a3x = 0.f, a3y = 0.f;

    int e = e0;
    for (; e + 4 <= e1; e += 4) {
        int r0 = sortr[e + 0], r1 = sortr[e + 1];
        int r2 = sortr[e + 2], r3 = sortr[e + 3];
        float2 v0 = __half22float2(*(const __half2*)&hs[(long)r0 * 128 + chb]);
        float2 v1 = __half22float2(*(const __half2*)&hs[(long)r1 * 128 + chb]);
        float2 v2 = __half22float2(*(const __half2*)&hs[(long)r2 * 128 + chb]);
        float2 v3 = __half22float2(*(const __half2*)&hs[(long)r3 * 128 + chb]);
        a0x += v0.x; a0y += v0.y;
        a1x += v1.x; a1y += v1.y;
        a2x += v2.x; a2y += v2.y;
        a3x += v3.x; a3y += v3.y;
    }
    for (; e < e1; ++e) {
        int r0 = sortr[e];
        float2 v0 = __half22float2(*(const __half2*)&hs[(long)r0 * 128 + chb]);
        a0x += v0.x; a0y += v0.y;
    }
    float ax = (a0x + a1x) + (a2x + a3x);
    float ay = (a0y + a1y) + (a2y + a3y);

    float dv = dinv[c];
    float2 b = *(const float2*)&bias[chb];
    float2 r;
    r.x = fmaxf(fmaf(ax, dv, b.x), 0.f);
    r.y = fmaxf(fmaf(ay, dv, b.y), 0.f);
    *(float2*)&out[(long)c * 128 + chb] = r;
}

// ---------------------------------------------------------------------------
// mean-pool stage 1: per-wave chunk of 32 sorted nodes, flush on graph change
__global__ __launch_bounds__(256) void pool_kernel(const float* __restrict__ h,
                                                   const int* __restrict__ batch,
                                                   float* __restrict__ pooled,
                                                   float* __restrict__ gcnt) {
    int wid = (blockIdx.x * 256 + threadIdx.x) >> 6;
    int lane = threadIdx.x & 63;
    long n0 = (long)wid * 32;
    if (n0 >= N_NODES) return;
    long n1 = n0 + 32;
    if (n1 > N_NODES) n1 = N_NODES;
    const long chb = 2 * lane;

    int g = batch[n0];
    float ax = 0.f, ay = 0.f;
    int run = 0;
    for (long n = n0; n < n1; ++n) {
        int gn = batch[n];
        if (gn != g) {
            atomicAdd(&pooled[g * 128 + chb], ax);
            atomicAdd(&pooled[g * 128 + chb + 1], ay);
            if (lane == 0) atomicAdd(&gcnt[g], (float)run);
            g = gn; ax = 0.f; ay = 0.f; run = 0;
        }
        float2 v = *(const float2*)&h[n * 128 + chb];
        ax += v.x; ay += v.y; run++;
    }
    atomicAdd(&pooled[g * 128 + chb], ax);
    atomicAdd(&pooled[g * 128 + chb + 1], ay);
    if (lane == 0) atomicAdd(&gcnt[g], (float)run);
}

// final: out[g][o] = (pooled[g][:]/cnt) @ Wlin[:,o] + blin[o]
__global__ void final_kernel(const float* __restrict__ pooled,
                             const float* __restrict__ gcnt,
                             const float* __restrict__ Wlin,
                             const float* __restrict__ blin,
                             float* __restrict__ out) {
    int t = threadIdx.x;
    if (t >= N_GRAPHS * 2) return;
    int g = t >> 1, o = t & 1;
    float c = gcnt[g];
    if (c < 1.f) c = 1.f;
    float s = 0.f;
    for (int k = 0; k < 128; ++k)
        s += (pooled[g * 128 + k] / c) * Wlin[k * 2 + o];
    out[g * 2 + o] = s + blin[o];
}

// ---------------------------------------------------------------------------
extern "C" void kernel_launch(void* const* d_in, const int* in_sizes, int n_in,
                              void* d_out, int out_size, void* d_ws, size_t ws_size,
                              hipStream_t stream) {
    const float* x     = (const float*)d_in[0];
    const int*   row   = (const int*)d_in[1];
    const int*   col   = row + N_EDGES;
    const int*   batch = (const int*)d_in[2];
    const float* W1    = (const float*)d_in[3];
    const float* b1    = (const float*)d_in[4];
    const float* W2    = (const float*)d_in[5];
    const float* b2    = (const float*)d_in[6];
    const float* Wlin  = (const float*)d_in[7];
    const float* blin  = (const float*)d_in[8];
    float* out = (float*)d_out;

    char* w = (char*)d_ws;
    size_t p = 0;
    auto alloc = [&](size_t bytes) -> void* {
        void* r = w + p;
        p += (bytes + 511) & ~(size_t)511;
        return r;
    };
    int*    off         = (int*)alloc((size_t)(N_NODES + 1) * 4);
    float*  dinv        = (float*)alloc((size_t)N_NODES * 4);
    int*    sortr       = (int*)alloc((size_t)N_EDGES * 4);
    int2*   pairs       = (int2*)alloc((size_t)N_EDGES * 8);
    int*    blockcnt    = (int*)alloc((size_t)NBLK * NB * 4);
    int*    buckettotal = (int*)alloc((size_t)NB * 4);
    int*    bucket_base = (int*)alloc((size_t)(NB + 1) * 4);
    __half* hs          = (__half*)alloc((size_t)N_NODES * 128 * 2);
    float*  hbuf        = (float*)alloc((size_t)N_NODES * 128 * 4);
    float*  pooled      = (float*)alloc((size_t)N_GRAPHS * 128 * 4);
    float*  gcnt        = (float*)alloc((size_t)N_GRAPHS * 4);
    (void)ws_size; (void)in_sizes; (void)n_in; (void)out_size;

    zero_kernel<<<(N_GRAPHS * 128 + 255) / 256, 256, 0, stream>>>(pooled, gcnt);

    // CSR build via deterministic binned counting sort
    sortcount_kernel<<<NBLK, 256, 0, stream>>>((const int4*)col, blockcnt);
    sortscan_kernel<<<NB, 256, 0, stream>>>(blockcnt, buckettotal);
    sortbase_kernel<<<1, 256, 0, stream>>>(buckettotal, bucket_base, off);
    sortscatter_kernel<<<NBLK, 256, 0, stream>>>((const int4*)row, (const int4*)col,
                                                 blockcnt, bucket_base, pairs);
    sortlocal_kernel<<<NB, 256, 0, stream>>>(pairs, bucket_base, buckettotal,
                                             sortr, off, dinv);

    // layer 1
    gemm_premul_kernel<<<(N_NODES + 63) / 64, 256, 0, stream>>>(x, W1, dinv, hs);
    agg_kernel<<<(N_NODES * 64 + 255) / 256, 256, 0, stream>>>(hs, sortr, off, dinv, b1, hbuf);
    // layer 2
    gemm_premul_kernel<<<(N_NODES + 63) / 64, 256, 0, stream>>>(hbuf, W2, dinv, hs);
    agg_kernel<<<(N_NODES * 64 + 255) / 256, 256, 0, stream>>>(hs, sortr, off, dinv, b2, hbuf);

    // pool + classifier
    pool_kernel<<<(((N_NODES + 31) / 32) * 64 + 255) / 256, 256, 0, stream>>>(hbuf, batch, pooled, gcnt);
    final_kernel<<<1, 128, 0, stream>>>(pooled, gcnt, Wlin, blin, out);
}

// Round 5
// 356.087 us; speedup vs baseline: 2.0574x; 1.3376x over previous
//
#include <hip/hip_runtime.h>
#include <hip/hip_bf16.h>
#include <hip/hip_fp16.h>

#define N_NODES  100000
#define N_EDGES  1600000
#define N_GRAPHS 64
// IN_CH = HIDDEN = 128, OUT_CH = 2

// Sort geometry: 256 buckets x 391 cols, 391 blocks x 4096 edges
#define NB       256          // buckets
#define BSZ      391          // cols per bucket (256*391 = 100096 >= 100000)
#define NE4      (N_EDGES/4)  // 400000 int4 elements
#define NBLK     391          // ceil(400000/1024) edge blocks (4096 edges each)

typedef __attribute__((ext_vector_type(4))) float    f32x4;
typedef __attribute__((ext_vector_type(8))) _Float16 f16x8;

// ---------------------------------------------------------------------------
// zero init: pooled[64*128] floats, gcnt[64] floats
__global__ __launch_bounds__(256) void zero_kernel(float* __restrict__ pooled,
                                                   float* __restrict__ gcnt) {
    int i = blockIdx.x * 256 + threadIdx.x;
    if (i < N_GRAPHS * 128) pooled[i] = 0.f;
    if (i < N_GRAPHS) gcnt[i] = 0.f;
}

// ---------------------------------------------------------------------------
// Pass A1: per-block 256-bucket histogram of col -> blockcnt[blk][bucket]
__global__ __launch_bounds__(256) void sortcount_kernel(const int4* __restrict__ col4,
                                                        int* __restrict__ blockcnt) {
    __shared__ int hist[NB];
    int t = threadIdx.x, blk = blockIdx.x;
    hist[t] = 0;
    __syncthreads();
#pragma unroll
    for (int j = 0; j < 4; ++j) {
        int i = blk * 1024 + j * 256 + t;
        if (i < NE4) {
            int4 c = col4[i];
            atomicAdd(&hist[c.x / BSZ], 1);
            atomicAdd(&hist[c.y / BSZ], 1);
            atomicAdd(&hist[c.z / BSZ], 1);
            atomicAdd(&hist[c.w / BSZ], 1);
        }
    }
    __syncthreads();
    blockcnt[blk * NB + t] = hist[t];
}

// Pass A2a: per-bucket exclusive scan across the 391 blocks (in place)
__global__ __launch_bounds__(256) void sortscan_kernel(int* __restrict__ blockcnt,
                                                       int* __restrict__ buckettotal) {
    int b = blockIdx.x, t = threadIdx.x;
    __shared__ int sc[256];
    int e0 = 2 * t, e1 = 2 * t + 1;
    int v0 = (e0 < NBLK) ? blockcnt[e0 * NB + b] : 0;
    int v1 = (e1 < NBLK) ? blockcnt[e1 * NB + b] : 0;
    int ps = v0 + v1;
    sc[t] = ps;
    __syncthreads();
    for (int d = 1; d < 256; d <<= 1) {
        int x = (t >= d) ? sc[t - d] : 0;
        __syncthreads();
        sc[t] += x;
        __syncthreads();
    }
    int ex = sc[t] - ps;
    if (e0 < NBLK) blockcnt[e0 * NB + b] = ex;
    if (e1 < NBLK) blockcnt[e1 * NB + b] = ex + v0;
    if (t == 255) buckettotal[b] = sc[255];
}

// Pass A2b: exclusive scan of 256 bucket totals -> bucket_base; off[N]=E
__global__ __launch_bounds__(256) void sortbase_kernel(const int* __restrict__ buckettotal,
                                                       int* __restrict__ bucket_base,
                                                       int* __restrict__ off) {
    __shared__ int sc[256];
    int t = threadIdx.x;
    int v = buckettotal[t];
    sc[t] = v;
    __syncthreads();
    for (int d = 1; d < 256; d <<= 1) {
        int x = (t >= d) ? sc[t - d] : 0;
        __syncthreads();
        sc[t] += x;
        __syncthreads();
    }
    bucket_base[t] = sc[t] - v;
    if (t == 255) {
        bucket_base[256] = sc[255];
        off[N_NODES] = N_EDGES;
    }
}

// Pass A3: scatter (row,col) pairs into bucket-grouped pairbuf (LDS cursors)
__global__ __launch_bounds__(256) void sortscatter_kernel(const int4* __restrict__ row4,
                                                          const int4* __restrict__ col4,
                                                          const int* __restrict__ blockpre,
                                                          const int* __restrict__ bucket_base,
                                                          int2* __restrict__ pairs) {
    __shared__ int cur[NB];
    int t = threadIdx.x, blk = blockIdx.x;
    cur[t] = bucket_base[t] + blockpre[blk * NB + t];
    __syncthreads();
#pragma unroll
    for (int j = 0; j < 4; ++j) {
        int i = blk * 1024 + j * 256 + t;
        if (i < NE4) {
            int4 r = row4[i];
            int4 c = col4[i];
            int p0 = atomicAdd(&cur[c.x / BSZ], 1); pairs[p0] = make_int2(r.x, c.x);
            int p1 = atomicAdd(&cur[c.y / BSZ], 1); pairs[p1] = make_int2(r.y, c.y);
            int p2 = atomicAdd(&cur[c.z / BSZ], 1); pairs[p2] = make_int2(r.z, c.z);
            int p3 = atomicAdd(&cur[c.w / BSZ], 1); pairs[p3] = make_int2(r.w, c.w);
        }
    }
}

// Pass B: per-bucket local sort -> sortr, off, dinv
__global__ __launch_bounds__(256) void sortlocal_kernel(const int2* __restrict__ pairs,
                                                        const int* __restrict__ bucket_base,
                                                        const int* __restrict__ buckettotal,
                                                        int* __restrict__ sortr,
                                                        int* __restrict__ off,
                                                        float* __restrict__ dinv) {
    int b = blockIdx.x, t = threadIdx.x;
    int base = bucket_base[b];
    int cnt  = buckettotal[b];
    int c0   = b * BSZ;
    int nc   = N_NODES - c0; if (nc > BSZ) nc = BSZ;

    __shared__ int hist[BSZ];
    __shared__ int sc[256];
    for (int i = t; i < nc; i += 256) hist[i] = 0;
    __syncthreads();
    for (int i = t; i < cnt; i += 256) {
        int2 pc = pairs[base + i];
        atomicAdd(&hist[pc.y - c0], 1);
    }
    __syncthreads();
    int e0 = 2 * t, e1 = 2 * t + 1;
    int h0 = (e0 < nc) ? hist[e0] : 0;
    int h1 = (e1 < nc) ? hist[e1] : 0;
    int ps = h0 + h1;
    sc[t] = ps;
    __syncthreads();
    for (int d = 1; d < 256; d <<= 1) {
        int x = (t >= d) ? sc[t - d] : 0;
        __syncthreads();
        sc[t] += x;
        __syncthreads();
    }
    int ex = sc[t] - ps;
    if (e0 < nc) { off[c0 + e0] = base + ex;      dinv[c0 + e0] = rsqrtf((float)h0 + 1.f); }
    if (e1 < nc) { off[c0 + e1] = base + ex + h0; dinv[c0 + e1] = rsqrtf((float)h1 + 1.f); }
    __syncthreads();
    if (e0 < nc) hist[e0] = base + ex;
    if (e1 < nc) hist[e1] = base + ex + h0;
    __syncthreads();
    for (int i = t; i < cnt; i += 256) {
        int2 pc = pairs[base + i];
        int pos = atomicAdd(&hist[pc.y - c0], 1);
        sortr[pos] = pc.x;
    }
}

// ---------------------------------------------------------------------------
// W pre-pack: fp32 [128][128] -> fragment-major fp16 for mfma_f32_16x16x32_f16
// frag f = j*4+s (j: 16-col tile, s: 32-k step); lane holds B[s*32+(l>>4)*8+i][j*16+(l&15)]
__global__ __launch_bounds__(256) void wpack_kernel(const float* __restrict__ W1,
                                                    const float* __restrict__ W2,
                                                    _Float16* __restrict__ Wp1,
                                                    _Float16* __restrict__ Wp2) {
    int tid = blockIdx.x * 256 + threadIdx.x;   // 0..4095
    const float* W = (tid < 2048) ? W1 : W2;
    _Float16*   Wp = (tid < 2048) ? Wp1 : Wp2;
    int t = tid & 2047;
    int f = t >> 6, lane = t & 63;
    int j = f >> 2, s = f & 3;
    int kb = s * 32 + (lane >> 4) * 8;
    int c  = j * 16 + (lane & 15);
#pragma unroll
    for (int i = 0; i < 8; ++i)
        Wp[(size_t)t * 8 + i] = (_Float16)W[(kb + i) * 128 + c];
}

// ---------------------------------------------------------------------------
// MFMA GEMM: hs[n][:] = fp16( dinv[n] * (X[n][:] @ W) )
// 4 waves/block, 16 nodes/wave; W fragments staged in 32KB LDS.
template<int FP16IN>
__global__ __launch_bounds__(256) void gemm_mfma_kernel(const void* __restrict__ Xv,
                                                        const _Float16* __restrict__ Wp,
                                                        const float* __restrict__ dinv,
                                                        _Float16* __restrict__ out) {
    __shared__ _Float16 Wl[16384];
    {
        const float4* src = (const float4*)Wp;
        float4* dst = (float4*)Wl;
        for (int i = threadIdx.x; i < 2048; i += 256) dst[i] = src[i];
    }
    __syncthreads();

    int wv = threadIdx.x >> 6, lane = threadIdx.x & 63;
    int tile = blockIdx.x * 4 + wv;
    if (tile >= N_NODES / 16) return;
    int n0 = tile * 16;
    int m = lane & 15, b = lane >> 4;

    // A fragments: a[s][i] = A[n0 + m][s*32 + b*8 + i]
    f16x8 a[4];
    if (FP16IN) {
        const _Float16* X = (const _Float16*)Xv;
        const _Float16* base = X + (size_t)(n0 + m) * 128 + b * 8;
#pragma unroll
        for (int s = 0; s < 4; ++s) a[s] = *(const f16x8*)(base + s * 32);
    } else {
        const float* X = (const float*)Xv;
        const float* base = X + (size_t)(n0 + m) * 128 + b * 8;
#pragma unroll
        for (int s = 0; s < 4; ++s) {
            float4 u = *(const float4*)(base + s * 32);
            float4 v = *(const float4*)(base + s * 32 + 4);
            f16x8 tt;
            tt[0] = (_Float16)u.x; tt[1] = (_Float16)u.y;
            tt[2] = (_Float16)u.z; tt[3] = (_Float16)u.w;
            tt[4] = (_Float16)v.x; tt[5] = (_Float16)v.y;
            tt[6] = (_Float16)v.z; tt[7] = (_Float16)v.w;
            a[s] = tt;
        }
    }

    f32x4 acc[8];
#pragma unroll
    for (int j = 0; j < 8; ++j) acc[j] = (f32x4){0.f, 0.f, 0.f, 0.f};

#pragma unroll
    for (int j = 0; j < 8; ++j) {
#pragma unroll
        for (int s = 0; s < 4; ++s) {
            f16x8 bf = *(const f16x8*)&Wl[(j * 4 + s) * 512 + lane * 8];
            acc[j] = __builtin_amdgcn_mfma_f32_16x16x32_f16(a[s], bf, acc[j], 0, 0, 0);
        }
    }

    // D layout: row = b*4 + reg, col = j*16 + m   (verified C/D mapping)
    float dv0 = dinv[n0 + b * 4 + 0];
    float dv1 = dinv[n0 + b * 4 + 1];
    float dv2 = dinv[n0 + b * 4 + 2];
    float dv3 = dinv[n0 + b * 4 + 3];
#pragma unroll
    for (int j = 0; j < 8; ++j) {
        _Float16* o = out + (size_t)(n0 + b * 4) * 128 + j * 16 + m;
        o[0 * 128] = (_Float16)(acc[j][0] * dv0);
        o[1 * 128] = (_Float16)(acc[j][1] * dv1);
        o[2 * 128] = (_Float16)(acc[j][2] * dv2);
        o[3 * 128] = (_Float16)(acc[j][3] * dv3);
    }
}

// ---------------------------------------------------------------------------
// out[c][:] = fp16( relu(dinv[c] * (sum_{r in N(c)} hs[r][:] + hs[c][:]) + bias) )
__global__ __launch_bounds__(256) void agg_kernel(const __half* __restrict__ hs,
                                                  const int* __restrict__ sortr,
                                                  const int* __restrict__ off,
                                                  const float* __restrict__ dinv,
                                                  const float* __restrict__ bias,
                                                  __half* __restrict__ out) {
    int wid = (blockIdx.x * 256 + threadIdx.x) >> 6;
    int lane = threadIdx.x & 63;
    if (wid >= N_NODES) return;
    const int c = wid;
    const int e0 = off[c], e1 = off[c + 1];
    const long chb = 2 * lane;

    float2 s = __half22float2(*(const __half2*)&hs[(long)c * 128 + chb]);
    float a0x = s.x, a0y = s.y;
    float a1x = 0.f, a1y = 0.f, a2x = 0.f, a2y = 0.f, a3x = 0.f, a3y = 0.f;

    int e = e0;
    for (; e + 4 <= e1; e += 4) {
        int r0 = sortr[e + 0], r1 = sortr[e + 1];
        int r2 = sortr[e + 2], r3 = sortr[e + 3];
        float2 v0 = __half22float2(*(const __half2*)&hs[(long)r0 * 128 + chb]);
        float2 v1 = __half22float2(*(const __half2*)&hs[(long)r1 * 128 + chb]);
        float2 v2 = __half22float2(*(const __half2*)&hs[(long)r2 * 128 + chb]);
        float2 v3 = __half22float2(*(const __half2*)&hs[(long)r3 * 128 + chb]);
        a0x += v0.x; a0y += v0.y;
        a1x += v1.x; a1y += v1.y;
        a2x += v2.x; a2y += v2.y;
        a3x += v3.x; a3y += v3.y;
    }
    for (; e < e1; ++e) {
        int r0 = sortr[e];
        float2 v0 = __half22float2(*(const __half2*)&hs[(long)r0 * 128 + chb]);
        a0x += v0.x; a0y += v0.y;
    }
    float ax = (a0x + a1x) + (a2x + a3x);
    float ay = (a0y + a1y) + (a2y + a3y);

    float dv = dinv[c];
    float2 bb = *(const float2*)&bias[chb];
    float rx = fmaxf(fmaf(ax, dv, bb.x), 0.f);
    float ry = fmaxf(fmaf(ay, dv, bb.y), 0.f);
    *(__half2*)&out[(long)c * 128 + chb] = __floats2half2_rn(rx, ry);
}

// ---------------------------------------------------------------------------
// mean-pool stage 1 (fp16 input): per-wave chunk of 32 sorted nodes
__global__ __launch_bounds__(256) void pool_kernel(const __half* __restrict__ h,
                                                   const int* __restrict__ batch,
                                                   float* __restrict__ pooled,
                                                   float* __restrict__ gcnt) {
    int wid = (blockIdx.x * 256 + threadIdx.x) >> 6;
    int lane = threadIdx.x & 63;
    long n0 = (long)wid * 32;
    if (n0 >= N_NODES) return;
    long n1 = n0 + 32;
    if (n1 > N_NODES) n1 = N_NODES;
    const long chb = 2 * lane;

    int g = batch[n0];
    float ax = 0.f, ay = 0.f;
    int run = 0;
    for (long n = n0; n < n1; ++n) {
        int gn = batch[n];
        if (gn != g) {
            atomicAdd(&pooled[g * 128 + chb], ax);
            atomicAdd(&pooled[g * 128 + chb + 1], ay);
            if (lane == 0) atomicAdd(&gcnt[g], (float)run);
            g = gn; ax = 0.f; ay = 0.f; run = 0;
        }
        float2 v = __half22float2(*(const __half2*)&h[n * 128 + chb]);
        ax += v.x; ay += v.y; run++;
    }
    atomicAdd(&pooled[g * 128 + chb], ax);
    atomicAdd(&pooled[g * 128 + chb + 1], ay);
    if (lane == 0) atomicAdd(&gcnt[g], (float)run);
}

// final: out[g][o] = (pooled[g][:]/cnt) @ Wlin[:,o] + blin[o]
__global__ void final_kernel(const float* __restrict__ pooled,
                             const float* __restrict__ gcnt,
                             const float* __restrict__ Wlin,
                             const float* __restrict__ blin,
                             float* __restrict__ out) {
    int t = threadIdx.x;
    if (t >= N_GRAPHS * 2) return;
    int g = t >> 1, o = t & 1;
    float c = gcnt[g];
    if (c < 1.f) c = 1.f;
    float s = 0.f;
    for (int k = 0; k < 128; ++k)
        s += (pooled[g * 128 + k] / c) * Wlin[k * 2 + o];
    out[g * 2 + o] = s + blin[o];
}

// ---------------------------------------------------------------------------
extern "C" void kernel_launch(void* const* d_in, const int* in_sizes, int n_in,
                              void* d_out, int out_size, void* d_ws, size_t ws_size,
                              hipStream_t stream) {
    const float* x     = (const float*)d_in[0];
    const int*   row   = (const int*)d_in[1];
    const int*   col   = row + N_EDGES;
    const int*   batch = (const int*)d_in[2];
    const float* W1    = (const float*)d_in[3];
    const float* b1    = (const float*)d_in[4];
    const float* W2    = (const float*)d_in[5];
    const float* b2    = (const float*)d_in[6];
    const float* Wlin  = (const float*)d_in[7];
    const float* blin  = (const float*)d_in[8];
    float* out = (float*)d_out;

    char* w = (char*)d_ws;
    size_t p = 0;
    auto alloc = [&](size_t bytes) -> void* {
        void* r = w + p;
        p += (bytes + 511) & ~(size_t)511;
        return r;
    };
    int*      off         = (int*)alloc((size_t)(N_NODES + 1) * 4);
    float*    dinv        = (float*)alloc((size_t)N_NODES * 4);
    int*      sortr       = (int*)alloc((size_t)N_EDGES * 4);
    int2*     pairs       = (int2*)alloc((size_t)N_EDGES * 8);
    int*      blockcnt    = (int*)alloc((size_t)NBLK * NB * 4);
    int*      buckettotal = (int*)alloc((size_t)NB * 4);
    int*      bucket_base = (int*)alloc((size_t)(NB + 1) * 4);
    _Float16* Wp1         = (_Float16*)alloc((size_t)128 * 128 * 2);
    _Float16* Wp2         = (_Float16*)alloc((size_t)128 * 128 * 2);
    __half*   hs          = (__half*)alloc((size_t)N_NODES * 128 * 2);
    __half*   hbuf        = (__half*)alloc((size_t)N_NODES * 128 * 2);
    float*    pooled      = (float*)alloc((size_t)N_GRAPHS * 128 * 4);
    float*    gcnt        = (float*)alloc((size_t)N_GRAPHS * 4);
    (void)ws_size; (void)in_sizes; (void)n_in; (void)out_size;

    zero_kernel<<<(N_GRAPHS * 128 + 255) / 256, 256, 0, stream>>>(pooled, gcnt);

    // CSR build via deterministic binned counting sort
    sortcount_kernel<<<NBLK, 256, 0, stream>>>((const int4*)col, blockcnt);
    sortscan_kernel<<<NB, 256, 0, stream>>>(blockcnt, buckettotal);
    sortbase_kernel<<<1, 256, 0, stream>>>(buckettotal, bucket_base, off);
    sortscatter_kernel<<<NBLK, 256, 0, stream>>>((const int4*)row, (const int4*)col,
                                                 blockcnt, bucket_base, pairs);
    sortlocal_kernel<<<NB, 256, 0, stream>>>(pairs, bucket_base, buckettotal,
                                             sortr, off, dinv);

    // weight pre-pack (fp16 fragment-major)
    wpack_kernel<<<16, 256, 0, stream>>>(W1, W2, Wp1, Wp2);

    // layer 1
    gemm_mfma_kernel<0><<<(N_NODES / 16 + 3) / 4, 256, 0, stream>>>(x, Wp1, dinv, (_Float16*)hs);
    agg_kernel<<<(N_NODES * 64 + 255) / 256, 256, 0, stream>>>(hs, sortr, off, dinv, b1, hbuf);
    // layer 2
    gemm_mfma_kernel<1><<<(N_NODES / 16 + 3) / 4, 256, 0, stream>>>(hbuf, Wp2, dinv, (_Float16*)hs);
    agg_kernel<<<(N_NODES * 64 + 255) / 256, 256, 0, stream>>>(hs, sortr, off, dinv, b2, hbuf);

    // pool + classifier
    pool_kernel<<<(((N_NODES + 31) / 32) * 64 + 255) / 256, 256, 0, stream>>>(hbuf, batch, pooled, gcnt);
    final_kernel<<<1, 128, 0, stream>>>(pooled, gcnt, Wlin, blin, out);
}

// Round 7
// 343.756 us; speedup vs baseline: 2.1312x; 1.0359x over previous
//
#include <hip/hip_runtime.h>
#include <hip/hip_bf16.h>
#include <hip/hip_fp16.h>

#define N_NODES  100000
#define N_EDGES  1600000
#define N_GRAPHS 64
// IN_CH = HIDDEN = 128, OUT_CH = 2

// Sort geometry: 256 buckets x 391 cols, 391 blocks x 4096 edges
#define NB       256
#define BSZ      391          // cols per bucket (256*391 >= 100000); fits 9 bits
#define NE4      (N_EDGES/4)
#define NBLK     391
#define ROWMASK  0x1FFFF      // 17 bits, N_NODES < 131072

typedef __attribute__((ext_vector_type(4))) float    f32x4;
typedef __attribute__((ext_vector_type(8))) _Float16 f16x8;

// ---------------------------------------------------------------------------
// Pass A1: per-block 256-bucket histogram of col
__global__ __launch_bounds__(256) void sortcount_kernel(const int4* __restrict__ col4,
                                                        int* __restrict__ blockcnt) {
    __shared__ int hist[NB];
    int t = threadIdx.x, blk = blockIdx.x;
    hist[t] = 0;
    __syncthreads();
#pragma unroll
    for (int j = 0; j < 4; ++j) {
        int i = blk * 1024 + j * 256 + t;
        if (i < NE4) {
            int4 c = col4[i];
            atomicAdd(&hist[c.x / BSZ], 1);
            atomicAdd(&hist[c.y / BSZ], 1);
            atomicAdd(&hist[c.z / BSZ], 1);
            atomicAdd(&hist[c.w / BSZ], 1);
        }
    }
    __syncthreads();
    blockcnt[blk * NB + t] = hist[t];
}

// Pass A2a: per-bucket exclusive scan across blocks
__global__ __launch_bounds__(256) void sortscan_kernel(int* __restrict__ blockcnt,
                                                       int* __restrict__ buckettotal) {
    int b = blockIdx.x, t = threadIdx.x;
    __shared__ int sc[256];
    int e0 = 2 * t, e1 = 2 * t + 1;
    int v0 = (e0 < NBLK) ? blockcnt[e0 * NB + b] : 0;
    int v1 = (e1 < NBLK) ? blockcnt[e1 * NB + b] : 0;
    int ps = v0 + v1;
    sc[t] = ps;
    __syncthreads();
    for (int d = 1; d < 256; d <<= 1) {
        int x = (t >= d) ? sc[t - d] : 0;
        __syncthreads();
        sc[t] += x;
        __syncthreads();
    }
    int ex = sc[t] - ps;
    if (e0 < NBLK) blockcnt[e0 * NB + b] = ex;
    if (e1 < NBLK) blockcnt[e1 * NB + b] = ex + v0;
    if (t == 255) buckettotal[b] = sc[255];
}

// Pass A2b: scan of bucket totals
__global__ __launch_bounds__(256) void sortbase_kernel(const int* __restrict__ buckettotal,
                                                       int* __restrict__ bucket_base,
                                                       int* __restrict__ off) {
    __shared__ int sc[256];
    int t = threadIdx.x;
    int v = buckettotal[t];
    sc[t] = v;
    __syncthreads();
    for (int d = 1; d < 256; d <<= 1) {
        int x = (t >= d) ? sc[t - d] : 0;
        __syncthreads();
        sc[t] += x;
        __syncthreads();
    }
    bucket_base[t] = sc[t] - v;
    if (t == 255) {
        bucket_base[256] = sc[255];
        off[N_NODES] = N_EDGES;
    }
}

// Pass A3: scatter packed (localcol<<17 | row) into bucket-grouped buffer
__global__ __launch_bounds__(256) void sortscatter_kernel(const int4* __restrict__ row4,
                                                          const int4* __restrict__ col4,
                                                          const int* __restrict__ blockpre,
                                                          const int* __restrict__ bucket_base,
                                                          int* __restrict__ pairs) {
    __shared__ int cur[NB];
    int t = threadIdx.x, blk = blockIdx.x;
    cur[t] = bucket_base[t] + blockpre[blk * NB + t];
    __syncthreads();
#pragma unroll
    for (int j = 0; j < 4; ++j) {
        int i = blk * 1024 + j * 256 + t;
        if (i < NE4) {
            int4 r = row4[i];
            int4 c = col4[i];
            int b0 = c.x / BSZ, b1 = c.y / BSZ, b2 = c.z / BSZ, b3 = c.w / BSZ;
            int p0 = atomicAdd(&cur[b0], 1); pairs[p0] = ((c.x - b0 * BSZ) << 17) | r.x;
            int p1 = atomicAdd(&cur[b1], 1); pairs[p1] = ((c.y - b1 * BSZ) << 17) | r.y;
            int p2 = atomicAdd(&cur[b2], 1); pairs[p2] = ((c.z - b2 * BSZ) << 17) | r.z;
            int p3 = atomicAdd(&cur[b3], 1); pairs[p3] = ((c.w - b3 * BSZ) << 17) | r.w;
        }
    }
}

// Pass B: per-bucket local sort -> sortr, off, dinv
__global__ __launch_bounds__(256) void sortlocal_kernel(const int* __restrict__ pairs,
                                                        const int* __restrict__ bucket_base,
                                                        const int* __restrict__ buckettotal,
                                                        int* __restrict__ sortr,
                                                        int* __restrict__ off,
                                                        float* __restrict__ dinv) {
    int b = blockIdx.x, t = threadIdx.x;
    int base = bucket_base[b];
    int cnt  = buckettotal[b];
    int c0   = b * BSZ;
    int nc   = N_NODES - c0; if (nc > BSZ) nc = BSZ;

    __shared__ int hist[BSZ];
    __shared__ int sc[256];
    for (int i = t; i < nc; i += 256) hist[i] = 0;
    __syncthreads();
    for (int i = t; i < cnt; i += 256) {
        int pc = pairs[base + i];
        atomicAdd(&hist[pc >> 17], 1);
    }
    __syncthreads();
    int e0 = 2 * t, e1 = 2 * t + 1;
    int h0 = (e0 < nc) ? hist[e0] : 0;
    int h1 = (e1 < nc) ? hist[e1] : 0;
    int ps = h0 + h1;
    sc[t] = ps;
    __syncthreads();
    for (int d = 1; d < 256; d <<= 1) {
        int x = (t >= d) ? sc[t - d] : 0;
        __syncthreads();
        sc[t] += x;
        __syncthreads();
    }
    int ex = sc[t] - ps;
    if (e0 < nc) { off[c0 + e0] = base + ex;      dinv[c0 + e0] = rsqrtf((float)h0 + 1.f); }
    if (e1 < nc) { off[c0 + e1] = base + ex + h0; dinv[c0 + e1] = rsqrtf((float)h1 + 1.f); }
    __syncthreads();
    if (e0 < nc) hist[e0] = base + ex;
    if (e1 < nc) hist[e1] = base + ex + h0;
    __syncthreads();
    for (int i = t; i < cnt; i += 256) {
        int pc = pairs[base + i];
        int pos = atomicAdd(&hist[pc >> 17], 1);
        sortr[pos] = pc & ROWMASK;
    }
}

// ---------------------------------------------------------------------------
// W pre-pack (fragment-major fp16 for mfma_f32_16x16x32_f16) + zero pooled/gcnt
__global__ __launch_bounds__(256) void wpack_zero_kernel(const float* __restrict__ W1,
                                                         const float* __restrict__ W2,
                                                         _Float16* __restrict__ Wp1,
                                                         _Float16* __restrict__ Wp2,
                                                         float* __restrict__ pooled,
                                                         float* __restrict__ gcnt) {
    int tid = blockIdx.x * 256 + threadIdx.x;   // 0..4095
    for (int i = tid; i < N_GRAPHS * 128 + N_GRAPHS; i += 4096) {
        if (i < N_GRAPHS * 128) pooled[i] = 0.f;
        else gcnt[i - N_GRAPHS * 128] = 0.f;
    }
    const float* W = (tid < 2048) ? W1 : W2;
    _Float16*   Wp = (tid < 2048) ? Wp1 : Wp2;
    int t = tid & 2047;
    int f = t >> 6, lane = t & 63;
    int j = f >> 2, s = f & 3;
    int kb = s * 32 + (lane >> 4) * 8;
    int c  = j * 16 + (lane & 15);
#pragma unroll
    for (int i = 0; i < 8; ++i)
        Wp[(size_t)t * 8 + i] = (_Float16)W[(kb + i) * 128 + c];
}

// ---------------------------------------------------------------------------
// MFMA GEMM layer1: hs[n][:] = fp16( dinv[n] * (X[n][:] @ W1) ), X fp32
__global__ __launch_bounds__(256) void gemm_mfma_kernel(const float* __restrict__ X,
                                                        const _Float16* __restrict__ Wp,
                                                        const float* __restrict__ dinv,
                                                        _Float16* __restrict__ out) {
    __shared__ _Float16 Wl[16384];
    {
        const float4* src = (const float4*)Wp;
        float4* dst = (float4*)Wl;
        for (int i = threadIdx.x; i < 2048; i += 256) dst[i] = src[i];
    }
    __syncthreads();

    int wv = threadIdx.x >> 6, lane = threadIdx.x & 63;
    int tile = blockIdx.x * 4 + wv;
    if (tile >= N_NODES / 16) return;
    int n0 = tile * 16;
    int m = lane & 15, b = lane >> 4;

    f16x8 a[4];
    const float* base = X + (size_t)(n0 + m) * 128 + b * 8;
#pragma unroll
    for (int s = 0; s < 4; ++s) {
        float4 u = *(const float4*)(base + s * 32);
        float4 v = *(const float4*)(base + s * 32 + 4);
        f16x8 tt;
        tt[0] = (_Float16)u.x; tt[1] = (_Float16)u.y;
        tt[2] = (_Float16)u.z; tt[3] = (_Float16)u.w;
        tt[4] = (_Float16)v.x; tt[5] = (_Float16)v.y;
        tt[6] = (_Float16)v.z; tt[7] = (_Float16)v.w;
        a[s] = tt;
    }

    f32x4 acc[8];
#pragma unroll
    for (int j = 0; j < 8; ++j) acc[j] = (f32x4){0.f, 0.f, 0.f, 0.f};
#pragma unroll
    for (int j = 0; j < 8; ++j)
#pragma unroll
        for (int s = 0; s < 4; ++s) {
            f16x8 bf = *(const f16x8*)&Wl[(j * 4 + s) * 512 + lane * 8];
            acc[j] = __builtin_amdgcn_mfma_f32_16x16x32_f16(a[s], bf, acc[j], 0, 0, 0);
        }

    float dv0 = dinv[n0 + b * 4 + 0];
    float dv1 = dinv[n0 + b * 4 + 1];
    float dv2 = dinv[n0 + b * 4 + 2];
    float dv3 = dinv[n0 + b * 4 + 3];
#pragma unroll
    for (int j = 0; j < 8; ++j) {
        _Float16* o = out + (size_t)(n0 + b * 4) * 128 + j * 16 + m;
        o[0 * 128] = (_Float16)(acc[j][0] * dv0);
        o[1 * 128] = (_Float16)(acc[j][1] * dv1);
        o[2 * 128] = (_Float16)(acc[j][2] * dv2);
        o[3 * 128] = (_Float16)(acc[j][3] * dv3);
    }
}

// ---------------------------------------------------------------------------
// Gather-accumulate one target row (float2 per lane) from fp16 messages
__device__ __forceinline__ float2 gather_row(const __half* __restrict__ hs,
                                             const int* __restrict__ sortr,
                                             int c, int e0, int e1, long chb) {
    float2 s = __half22float2(*(const __half2*)&hs[(long)c * 128 + chb]);
    float a0x = s.x, a0y = s.y;
    float a1x = 0.f, a1y = 0.f, a2x = 0.f, a2y = 0.f, a3x = 0.f, a3y = 0.f;
    int e = e0;
    for (; e + 4 <= e1; e += 4) {
        int r0 = sortr[e + 0], r1 = sortr[e + 1];
        int r2 = sortr[e + 2], r3 = sortr[e + 3];
        float2 v0 = __half22float2(*(const __half2*)&hs[(long)r0 * 128 + chb]);
        float2 v1 = __half22float2(*(const __half2*)&hs[(long)r1 * 128 + chb]);
        float2 v2 = __half22float2(*(const __half2*)&hs[(long)r2 * 128 + chb]);
        float2 v3 = __half22float2(*(const __half2*)&hs[(long)r3 * 128 + chb]);
        a0x += v0.x; a0y += v0.y;
        a1x += v1.x; a1y += v1.y;
        a2x += v2.x; a2y += v2.y;
        a3x += v3.x; a3y += v3.y;
    }
    for (; e < e1; ++e) {
        int r0 = sortr[e];
        float2 v0 = __half22float2(*(const __half2*)&hs[(long)r0 * 128 + chb]);
        a0x += v0.x; a0y += v0.y;
    }
    float2 r;
    r.x = (a0x + a1x) + (a2x + a3x);
    r.y = (a0y + a1y) + (a2y + a3y);
    return r;
}

// ---------------------------------------------------------------------------
// Fused agg(layer1) + gemm(W2): block = 16 targets, 4 waves x 4 targets.
// h2 = relu(dinv_c * gather + b1)  (fp32, LDS)  ->  hs2 = dinv * (h2 @ W2)
__global__ __launch_bounds__(256) void agg_gemm_kernel(const __half* __restrict__ hs,
                                                       const int* __restrict__ sortr,
                                                       const int* __restrict__ off,
                                                       const float* __restrict__ dinv,
                                                       const float* __restrict__ bias,   // b1
                                                       const _Float16* __restrict__ Wp,  // W2 packed
                                                       _Float16* __restrict__ out) {
    __shared__ float rowbuf[16 * 132];   // stride 132: 16B-aligned rows, ~2-way banks
    int t = threadIdx.x;
    int wv = t >> 6, lane = t & 63;
    int c0 = blockIdx.x * 16;
    const long chb = 2 * (long)lane;
    float2 bb = *(const float2*)&bias[chb];

#pragma unroll
    for (int i = 0; i < 4; ++i) {
        int c = c0 + wv * 4 + i;
        float2 g = gather_row(hs, sortr, c, off[c], off[c + 1], chb);
        float dv = dinv[c];
        float rx = fmaxf(fmaf(g.x, dv, bb.x), 0.f);
        float ry = fmaxf(fmaf(g.y, dv, bb.y), 0.f);
        rowbuf[(wv * 4 + i) * 132 + 2 * lane]     = rx;
        rowbuf[(wv * 4 + i) * 132 + 2 * lane + 1] = ry;
    }
    __syncthreads();

    int m = lane & 15, b = lane >> 4;
    f16x8 a[4];
#pragma unroll
    for (int s = 0; s < 4; ++s) {
        const float* rb = &rowbuf[m * 132 + s * 32 + b * 8];
        float4 u = *(const float4*)rb;
        float4 v = *(const float4*)(rb + 4);
        f16x8 tt;
        tt[0] = (_Float16)u.x; tt[1] = (_Float16)u.y;
        tt[2] = (_Float16)u.z; tt[3] = (_Float16)u.w;
        tt[4] = (_Float16)v.x; tt[5] = (_Float16)v.y;
        tt[6] = (_Float16)v.z; tt[7] = (_Float16)v.w;
        a[s] = tt;
    }

    f32x4 acc[2];
    acc[0] = (f32x4){0.f, 0.f, 0.f, 0.f};
    acc[1] = (f32x4){0.f, 0.f, 0.f, 0.f};
#pragma unroll
    for (int jj = 0; jj < 2; ++jj) {
        int j = wv * 2 + jj;
#pragma unroll
        for (int s = 0; s < 4; ++s) {
            f16x8 bf = *(const f16x8*)&Wp[((size_t)(j * 4 + s) * 64 + lane) * 8];
            acc[jj] = __builtin_amdgcn_mfma_f32_16x16x32_f16(a[s], bf, acc[jj], 0, 0, 0);
        }
    }

    float dv0 = dinv[c0 + b * 4 + 0];
    float dv1 = dinv[c0 + b * 4 + 1];
    float dv2 = dinv[c0 + b * 4 + 2];
    float dv3 = dinv[c0 + b * 4 + 3];
#pragma unroll
    for (int jj = 0; jj < 2; ++jj) {
        int j = wv * 2 + jj;
        _Float16* o = out + (size_t)(c0 + b * 4) * 128 + j * 16 + m;
        o[0 * 128] = (_Float16)(acc[jj][0] * dv0);
        o[1 * 128] = (_Float16)(acc[jj][1] * dv1);
        o[2 * 128] = (_Float16)(acc[jj][2] * dv2);
        o[3 * 128] = (_Float16)(acc[jj][3] * dv3);
    }
}

// ---------------------------------------------------------------------------
// Fused agg(layer2) + mean-pool accumulate: block = 16 targets.
// h3 = relu(dinv_c * gather + b2); pooled[batch[c]] += h3 (block-reduced).
__global__ __launch_bounds__(256) void agg_pool_kernel(const __half* __restrict__ hs2,
                                                       const int* __restrict__ sortr,
                                                       const int* __restrict__ off,
                                                       const float* __restrict__ dinv,
                                                       const float* __restrict__ bias,  // b2
                                                       const int* __restrict__ batch,
                                                       float* __restrict__ pooled,
                                                       float* __restrict__ gcnt) {
    __shared__ float redA[4][128];
    __shared__ float redB[4][128];
    int t = threadIdx.x;
    int wv = t >> 6, lane = t & 63;
    int c0 = blockIdx.x * 16;
    const long chb = 2 * (long)lane;
    float2 bb = *(const float2*)&bias[chb];

    int g0   = batch[c0];
    int gend = batch[c0 + 15];
    bool slow = (gend > g0 + 1);   // block spans >2 graphs (defensive; ~never)

    float2 accA = make_float2(0.f, 0.f);
    float2 accB = make_float2(0.f, 0.f);

#pragma unroll
    for (int i = 0; i < 4; ++i) {
        int c = c0 + wv * 4 + i;
        float2 g = gather_row(hs2, sortr, c, off[c], off[c + 1], chb);
        float dv = dinv[c];
        float rx = fmaxf(fmaf(g.x, dv, bb.x), 0.f);
        float ry = fmaxf(fmaf(g.y, dv, bb.y), 0.f);
        int gg = batch[c];
        if (!slow) {
            if (gg == g0) { accA.x += rx; accA.y += ry; }
            else          { accB.x += rx; accB.y += ry; }
        } else {
            atomicAdd(&pooled[(size_t)gg * 128 + chb],     rx);
            atomicAdd(&pooled[(size_t)gg * 128 + chb + 1], ry);
        }
    }

    if (!slow) {
        redA[wv][2 * lane]     = accA.x;
        redA[wv][2 * lane + 1] = accA.y;
        redB[wv][2 * lane]     = accB.x;
        redB[wv][2 * lane + 1] = accB.y;
        __syncthreads();
        if (wv == 0) {
            int ch0 = 2 * lane, ch1 = 2 * lane + 1;
            float sA0 = (redA[0][ch0] + redA[1][ch0]) + (redA[2][ch0] + redA[3][ch0]);
            float sA1 = (redA[0][ch1] + redA[1][ch1]) + (redA[2][ch1] + redA[3][ch1]);
            atomicAdd(&pooled[(size_t)g0 * 128 + ch0], sA0);
            atomicAdd(&pooled[(size_t)g0 * 128 + ch1], sA1);
            if (gend != g0) {
                float sB0 = (redB[0][ch0] + redB[1][ch0]) + (redB[2][ch0] + redB[3][ch0]);
                float sB1 = (redB[0][ch1] + redB[1][ch1]) + (redB[2][ch1] + redB[3][ch1]);
                atomicAdd(&pooled[(size_t)gend * 128 + ch0], sB0);
                atomicAdd(&pooled[(size_t)gend * 128 + ch1], sB1);
            }
        }
        if (t == 0) {
            int nB = 0;
#pragma unroll
            for (int k = 0; k < 16; ++k) nB += (batch[c0 + k] != g0) ? 1 : 0;
            atomicAdd(&gcnt[g0], (float)(16 - nB));
            if (nB) atomicAdd(&gcnt[gend], (float)nB);
        }
    } else {
        if (t == 0)
            for (int k = 0; k < 16; ++k) atomicAdd(&gcnt[batch[c0 + k]], 1.f);
    }
}

// final: out[g][o] = (pooled[g][:]/cnt) @ Wlin[:,o] + blin[o]
__global__ void final_kernel(const float* __restrict__ pooled,
                             const float* __restrict__ gcnt,
                             const float* __restrict__ Wlin,
                             const float* __restrict__ blin,
                             float* __restrict__ out) {
    int t = threadIdx.x;
    if (t >= N_GRAPHS * 2) return;
    int g = t >> 1, o = t & 1;
    float c = gcnt[g];
    if (c < 1.f) c = 1.f;
    float s = 0.f;
    for (int k = 0; k < 128; ++k)
        s += (pooled[g * 128 + k] / c) * Wlin[k * 2 + o];
    out[g * 2 + o] = s + blin[o];
}

// ---------------------------------------------------------------------------
extern "C" void kernel_launch(void* const* d_in, const int* in_sizes, int n_in,
                              void* d_out, int out_size, void* d_ws, size_t ws_size,
                              hipStream_t stream) {
    const float* x     = (const float*)d_in[0];
    const int*   row   = (const int*)d_in[1];
    const int*   col   = row + N_EDGES;
    const int*   batch = (const int*)d_in[2];
    const float* W1    = (const float*)d_in[3];
    const float* b1    = (const float*)d_in[4];
    const float* W2    = (const float*)d_in[5];
    const float* b2    = (const float*)d_in[6];
    const float* Wlin  = (const float*)d_in[7];
    const float* blin  = (const float*)d_in[8];
    float* out = (float*)d_out;

    char* w = (char*)d_ws;
    size_t p = 0;
    auto alloc = [&](size_t bytes) -> void* {
        void* r = w + p;
        p += (bytes + 511) & ~(size_t)511;
        return r;
    };
    int*      off         = (int*)alloc((size_t)(N_NODES + 1) * 4);
    float*    dinv        = (float*)alloc((size_t)N_NODES * 4);
    int*      sortr       = (int*)alloc((size_t)N_EDGES * 4);
    int*      pairs       = (int*)alloc((size_t)N_EDGES * 4);
    int*      blockcnt    = (int*)alloc((size_t)NBLK * NB * 4);
    int*      buckettotal = (int*)alloc((size_t)NB * 4);
    int*      bucket_base = (int*)alloc((size_t)(NB + 1) * 4);
    _Float16* Wp1         = (_Float16*)alloc((size_t)128 * 128 * 2);
    _Float16* Wp2         = (_Float16*)alloc((size_t)128 * 128 * 2);
    __half*   hs          = (__half*)alloc((size_t)N_NODES * 128 * 2);
    __half*   hs2         = (__half*)alloc((size_t)N_NODES * 128 * 2);
    float*    pooled      = (float*)alloc((size_t)N_GRAPHS * 128 * 4);
    float*    gcnt        = (float*)alloc((size_t)N_GRAPHS * 4);
    (void)ws_size; (void)in_sizes; (void)n_in; (void)out_size;

    // CSR build (deterministic binned counting sort) + weight pack + zero
    sortcount_kernel<<<NBLK, 256, 0, stream>>>((const int4*)col, blockcnt);
    sortscan_kernel<<<NB, 256, 0, stream>>>(blockcnt, buckettotal);
    sortbase_kernel<<<1, 256, 0, stream>>>(buckettotal, bucket_base, off);
    sortscatter_kernel<<<NBLK, 256, 0, stream>>>((const int4*)row, (const int4*)col,
                                                 blockcnt, bucket_base, pairs);
    sortlocal_kernel<<<NB, 256, 0, stream>>>(pairs, bucket_base, buckettotal,
                                             sortr, off, dinv);
    wpack_zero_kernel<<<16, 256, 0, stream>>>(W1, W2, Wp1, Wp2, pooled, gcnt);

    // layer 1 GEMM (MFMA, dinv premul)
    gemm_mfma_kernel<<<(N_NODES / 16 + 3) / 4, 256, 0, stream>>>(x, Wp1, dinv, (_Float16*)hs);
    // fused agg1 + gemm2
    agg_gemm_kernel<<<N_NODES / 16, 256, 0, stream>>>(hs, sortr, off, dinv, b1, Wp2,
                                                      (_Float16*)hs2);
    // fused agg2 + mean-pool accumulate
    agg_pool_kernel<<<N_NODES / 16, 256, 0, stream>>>(hs2, sortr, off, dinv, b2, batch,
                                                      pooled, gcnt);
    // classifier
    final_kernel<<<1, 128, 0, stream>>>(pooled, gcnt, Wlin, blin, out);
}